// Round 8
// baseline (650.245 us; speedup 1.0000x reference)
//
#include <hip/hip_runtime.h>

typedef __attribute__((ext_vector_type(8))) __bf16 bf16x8;
typedef __attribute__((ext_vector_type(4))) float f32x4;

#define N_ 1024
#define C_ 64
#define BP_ 48

static __device__ __forceinline__ unsigned short f2bf(float f) {
    __bf16 b = (__bf16)f;
    return __builtin_bit_cast(unsigned short, b);
}
static __device__ __forceinline__ unsigned int pack2(float a, float b) {
    return (unsigned int)f2bf(a) | ((unsigned int)f2bf(b) << 16);
}

// ---------------------------------------------------------------------------
// K0 gat_pack: DUMB streaming pass.  Lesson of R0-R7: every compute kernel
// with a dependency chain read A at ~1-1.5TB/s regardless of schedule; the
// harness fill kernel (independent grid-stride stores) does 6.5TB/s at 10%
// occupancy, and the m13 copy ubench does 6.29TB/s.  So ALL heavy traffic
// moves here: A -> outA verbatim copy (exact passthrough) + u16 bitmask
// per 16-col segment (A in {0,1}).  2048x256, exactly 6 independent
// segments/thread, NT loads/stores, zero cross-iteration deps.
// Amask[seg], seg = (bp*N + row)*64 + col/16  (linear = copy order).
// ---------------------------------------------------------------------------
__global__ __launch_bounds__(256) void gat_pack(
    const float* __restrict__ Ag, float* __restrict__ outA,
    unsigned short* __restrict__ Amask)
{
    const size_t seg0 = (size_t)blockIdx.x * 256 + threadIdx.x;
    const size_t stride = (size_t)2048 * 256;
    // nseg = 48*1024*1024/16 = 3,145,728 = 6 * 524,288 exactly
    #pragma unroll 2
    for (int it = 0; it < 6; ++it) {
        const size_t seg = seg0 + (size_t)it * stride;
        const f32x4* src = (const f32x4*)(Ag + seg * 16);
        f32x4* dst = (f32x4*)(outA + seg * 16);
        unsigned int bits = 0;
        #pragma unroll
        for (int j = 0; j < 4; ++j) {
            f32x4 a = __builtin_nontemporal_load(src + j);
            __builtin_nontemporal_store(a, dst + j);
            #pragma unroll
            for (int r = 0; r < 4; ++r)
                bits |= (a[r] != 0.f ? 1u : 0u) << (4 * j + r);
        }
        Amask[seg] = (unsigned short)bits;
    }
}

// ---------------------------------------------------------------------------
// K1: v1/v2 fold of W_emb, s1/s2 per node, per-wave max(s2) -> M2part, and
// permuted bf16 transpose xP (light version, no A traffic).
// grid (16 j-tiles, 48 bp), block 256 (4 waves).
// ---------------------------------------------------------------------------
__global__ __launch_bounds__(256) void gat_pre(
    const float* __restrict__ x, const float* __restrict__ Wemb,
    const float* __restrict__ a1, const float* __restrict__ a2,
    float* __restrict__ s1g, float* __restrict__ s2g,
    unsigned short* __restrict__ xP, float* __restrict__ M2part)
{
    __shared__ float xs[64][65];
    __shared__ float vs[2][64];
    const int t = threadIdx.x, l = t & 63, w = t >> 6;
    const int j0 = blockIdx.x * 64;
    const int bp = blockIdx.y;

    if (w == 0) {   // v1[c]=sum_h a1[h]*W_emb[h][c]  (x_emb folds away)
        float v1 = 0.f, v2 = 0.f;
        #pragma unroll 8
        for (int h = 0; h < 64; ++h) {
            float we = Wemb[h * 64 + l];
            v1 = fmaf(a1[h], we, v1);
            v2 = fmaf(a2[h], we, v2);
        }
        vs[0][l] = v1; vs[1][l] = v2;
    }
    const float* xb = x + ((size_t)bp * N_ + j0) * C_;
    #pragma unroll
    for (int it = 0; it < 16; ++it)
        xs[it * 4 + w][l] = xb[(it * 4 + w) * C_ + l];
    __syncthreads();

    const int jr = t >> 2, c0 = (t & 3) * 16;
    float p1 = 0.f, p2 = 0.f;
    #pragma unroll
    for (int k = 0; k < 16; ++k) {
        float xv = xs[jr][c0 + k];
        p1 = fmaf(xv, vs[0][c0 + k], p1);
        p2 = fmaf(xv, vs[1][c0 + k], p2);
    }
    p1 += __shfl_xor(p1, 1); p1 += __shfl_xor(p1, 2);
    p2 += __shfl_xor(p2, 1); p2 += __shfl_xor(p2, 2);
    if ((l & 3) == 0) {
        s1g[bp * N_ + j0 + jr] = p1;
        s2g[bp * N_ + j0 + jr] = p2;
    }
    float m = p2;
    m = fmaxf(m, __shfl_xor(m, 4));
    m = fmaxf(m, __shfl_xor(m, 8));
    m = fmaxf(m, __shfl_xor(m, 16));
    m = fmaxf(m, __shfl_xor(m, 32));
    if (l == 0) M2part[bp * 64 + blockIdx.x * 4 + w] = m;

    // permuted transpose store: source j_local = part*16 + 4m + i  ->
    // dest  d = (part>>1)*32 + (part&1)*4 + m*8 + i   (within this 64-chunk)
    const int c = t >> 2, part = t & 3;
    unsigned short* dstb = xP + (size_t)bp * C_ * N_ + (size_t)c * N_ + j0 +
                           (part >> 1) * 32 + (part & 1) * 4;
    #pragma unroll
    for (int m_ = 0; m_ < 4; ++m_) {
        unsigned int lo = pack2(xs[part * 16 + 4 * m_ + 0][c],
                                xs[part * 16 + 4 * m_ + 1][c]);
        unsigned int hi = pack2(xs[part * 16 + 4 * m_ + 2][c],
                                xs[part * 16 + 4 * m_ + 3][c]);
        *(uint2*)&dstb[m_ * 8] = make_uint2(lo, hi);
    }
}

// ---------------------------------------------------------------------------
// K2 v9: compute-only fused.  All outA traffic gone (gat_pack copies it).
// Remaining global: 8B mask word per (row,chunk) from the L3-hot 6.3MB
// bitmask, xP from L2, 12.6MB out writes in the epilogue.  The latency
// chain that defeated R0-R7's schedules now has almost no memory to wait
// for.  P = bit ? Ev : 0 is bit-identical to Av*Ev (A in {0,1}).
// grid (16,48), block 256 (4 indep waves), launch_bounds(256,3).
// ---------------------------------------------------------------------------
#define SB() __builtin_amdgcn_sched_barrier(0)

__global__ __launch_bounds__(256, 3) void gat_fused(
    const unsigned short* __restrict__ Amask,
    const unsigned short* __restrict__ xP,
    const float* __restrict__ s1g, const float* __restrict__ s2g,
    const float* __restrict__ M2part,
    const float* __restrict__ Wlin, float* __restrict__ out)
{
    __shared__ unsigned short aggLDS[4][16][72]; // 9 KB  epilogue only (pad 8)
    __shared__ float s2lds[1024];                // 4 KB  s2 row, block-shared
    __shared__ float lsLDS[4][16];               // 256 B per-wave row sums

    const int t = threadIdx.x, l = t & 63, w = t >> 6;
    const int i15 = l & 15, q = l >> 4;
    const int bp = blockIdx.y;
    const int ibase = blockIdx.x * 64 + w * 16;

    // stage s2 (1024 f32) to LDS, block-wide
    *(f32x4*)&s2lds[4 * t] = *(const f32x4*)&s2g[bp * N_ + 4 * t];

    float m2v = M2part[bp * 64 + l];
    #pragma unroll
    for (int off = 32; off >= 1; off >>= 1)
        m2v = fmaxf(m2v, __shfl_xor(m2v, off));
    const float M2 = m2v;
    // this lane owns output row (ibase + i15) exclusively
    const float s1_l = s1g[bp * N_ + ibase + i15];
    const float zr = s1_l + M2;
    const float mv = fmaxf(zr, 0.01f * zr);   // global max_j leaky(s1+s2j)

    __syncthreads();   // s2lds ready (only barrier before epilogue)

    const unsigned short* xProw = xP + (size_t)bp * C_ * N_ + (size_t)i15 * N_ + q * 8;
    // mask row: u16[64] per row; chunk k bits = 8B at offset k
    const uint2* Mrow = (const uint2*)(Amask + ((size_t)bp * N_ + ibase + i15) * 64);

    f32x4 acc[4] = {};          // D: row q*4+r, col nt*16+i15
    float ls = 0.f;             // partial row-sum of row i15 (this lane's j's)
    const int q4 = q * 4;

    bf16x8 Xa[8], Xb[8];        // xP fragment double-buffer [s*4+nt]
    uint2 Ma, Mb;               // mask double-buffer (8B per chunk)

#define LOADX(Xc, kk) do {                                                    \
    _Pragma("unroll")                                                         \
    for (int nt = 0; nt < 4; ++nt)                                            \
        _Pragma("unroll")                                                     \
        for (int s = 0; s < 2; ++s)                                           \
            Xc[s * 4 + nt] = *(const bf16x8*)&xProw[(size_t)nt * 16 * N_ +    \
                                                    (kk) * 64 + s * 32];      \
    } while (0)

// consume chunk kk from Xc (xP regs) and Mc (mask bits), loaded >=1 iter ago
#define CONSUME(Xc, Mc, kk) do {                                              \
    const int jrel = (kk) * 64;                                               \
    f32x4 Ev[4];                                                              \
    _Pragma("unroll")                                                         \
    for (int g = 0; g < 4; ++g) {                                             \
        const f32x4 s2v = *(const f32x4*)&s2lds[jrel + g * 16 + q4];          \
        _Pragma("unroll")                                                     \
        for (int r = 0; r < 4; ++r) {                                         \
            float zz = s1_l + s2v[r];                                         \
            zz = fmaxf(zz, 0.01f * zz);                                       \
            Ev[g][r] = __expf(zz - mv);                                       \
        }                                                                     \
    }                                                                         \
    SB();                                                                     \
    f32x4 P[4];                                                               \
    _Pragma("unroll")                                                         \
    for (int g = 0; g < 4; ++g) {                                             \
        const unsigned int wbits = (g < 2) ? Mc.x : Mc.y;                     \
        const int sh = (g & 1) * 16 + q4;                                     \
        _Pragma("unroll")                                                     \
        for (int r = 0; r < 4; ++r) {                                         \
            float bf = (float)((wbits >> (sh + r)) & 1u);                     \
            P[g][r] = bf * Ev[g][r];                                          \
            ls += P[g][r];                                                    \
        }                                                                     \
    }                                                                         \
    uint4 u0 = make_uint4(pack2(P[0][0], P[0][1]), pack2(P[0][2], P[0][3]),   \
                          pack2(P[1][0], P[1][1]), pack2(P[1][2], P[1][3]));  \
    uint4 u1 = make_uint4(pack2(P[2][0], P[2][1]), pack2(P[2][2], P[2][3]),   \
                          pack2(P[3][0], P[3][1]), pack2(P[3][2], P[3][3]));  \
    bf16x8 af0 = __builtin_bit_cast(bf16x8, u0);                              \
    bf16x8 af1 = __builtin_bit_cast(bf16x8, u1);                              \
    _Pragma("unroll")                                                         \
    for (int nt = 0; nt < 4; ++nt)                                            \
        acc[nt] = __builtin_amdgcn_mfma_f32_16x16x32_bf16(af0, Xc[nt],        \
                                                          acc[nt], 0, 0, 0);  \
    _Pragma("unroll")                                                         \
    for (int nt = 0; nt < 4; ++nt)                                            \
        acc[nt] = __builtin_amdgcn_mfma_f32_16x16x32_bf16(af1, Xc[4 + nt],    \
                                                          acc[nt], 0, 0, 0);  \
    } while (0)

    // prime chunk 0
    LOADX(Xa, 0); Ma = Mrow[0];
    #pragma unroll 1
    for (int k = 0; k < 16; k += 2) {
        SB();
        Mb = Mrow[k + 1]; LOADX(Xb, k + 1);
        SB();
        CONSUME(Xa, Ma, k);
        SB();
        if (k + 2 < 16) { Ma = Mrow[k + 2]; LOADX(Xa, k + 2); }
        SB();
        CONSUME(Xb, Mb, k + 1);
    }
    SB();
#undef LOADX
#undef CONSUME

    // row-sum: lane has partial of row i15; combine across the 4 q-groups
    ls += __shfl_xor(ls, 16);
    ls += __shfl_xor(ls, 32);
    if (q == 0) lsLDS[w][i15] = ls;
    const f32x4 lsq = *(const f32x4*)&lsLDS[w][4 * q];   // rows 4q..4q+3

    // ---- epilogue: agg = acc/l, LDS round-trip to A-layout, @W_lin^T, sigmoid
    unsigned short* aggl = &aggLDS[w][0][0];   // stride 72
    #pragma unroll
    for (int nt = 0; nt < 4; ++nt)
        #pragma unroll
        for (int r = 0; r < 4; ++r)
            aggl[(q * 4 + r) * 72 + nt * 16 + i15] = f2bf(acc[nt][r] / lsq[r]);

    f32x4 d2[4] = {};
    #pragma unroll
    for (int s = 0; s < 2; ++s) {
        bf16x8 af = *(const bf16x8*)&aggl[i15 * 72 + s * 32 + q * 8];
        #pragma unroll
        for (int nt = 0; nt < 4; ++nt) {
            const float* wp = Wlin + (size_t)(nt * 16 + i15) * C_ + s * 32 + q * 8;
            f32x4 w0 = *(const f32x4*)wp;
            f32x4 w1 = *(const f32x4*)(wp + 4);
            bf16x8 bfr;
            #pragma unroll
            for (int jj = 0; jj < 4; ++jj) { bfr[jj] = (__bf16)w0[jj]; bfr[4 + jj] = (__bf16)w1[jj]; }
            d2[nt] = __builtin_amdgcn_mfma_f32_16x16x32_bf16(af, bfr, d2[nt], 0, 0, 0);
        }
    }
    float* orow = out + ((size_t)bp * N_ + ibase) * C_;
    #pragma unroll
    for (int nt = 0; nt < 4; ++nt)
        #pragma unroll
        for (int r = 0; r < 4; ++r)
            orow[(size_t)(q * 4 + r) * C_ + nt * 16 + i15] =
                1.f / (1.f + __expf(-d2[nt][r]));
}

extern "C" void kernel_launch(void* const* d_in, const int* in_sizes, int n_in,
                              void* d_out, int out_size, void* d_ws, size_t ws_size,
                              hipStream_t stream) {
    const float* x    = (const float*)d_in[0];
    const float* Ag   = (const float*)d_in[1];
    const float* Wemb = (const float*)d_in[2];
    const float* a1   = (const float*)d_in[3];
    const float* a2   = (const float*)d_in[4];
    const float* Wlin = (const float*)d_in[5];
    float* out  = (float*)d_out;
    float* outA = out + (size_t)BP_ * N_ * C_;   // tuple output #2: A passthrough

    // ws layout (~13 MB total)
    float* s1g = (float*)d_ws;                               // 48K f32
    float* s2g = s1g + BP_ * N_;                             // 48K f32
    float* M2part = s2g + BP_ * N_;                          // 48*64 f32
    unsigned short* xP = (unsigned short*)(M2part + BP_ * 64);   // 6.3MB bf16
    unsigned short* Amask = xP + (size_t)BP_ * C_ * N_;          // 6.3MB bits

    gat_pack<<<dim3(2048), dim3(256), 0, stream>>>(Ag, outA, Amask);
    gat_pre<<<dim3(16, BP_), dim3(256), 0, stream>>>(x, Wemb, a1, a2,
                                                     s1g, s2g, xP, M2part);
    gat_fused<<<dim3(16, BP_), dim3(256), 0, stream>>>(Amask, xP, s1g, s2g,
                                                       M2part, Wlin, out);
}

// Round 9
// 414.752 us; speedup vs baseline: 1.5678x; 1.5678x over previous
//
#include <hip/hip_runtime.h>

typedef __attribute__((ext_vector_type(8))) __bf16 bf16x8;
typedef __attribute__((ext_vector_type(4))) float f32x4;

#define N_ 1024
#define C_ 64
#define BP_ 48

static __device__ __forceinline__ unsigned short f2bf(float f) {
    __bf16 b = (__bf16)f;
    return __builtin_bit_cast(unsigned short, b);
}
static __device__ __forceinline__ unsigned int pack2(float a, float b) {
    return (unsigned int)f2bf(a) | ((unsigned int)f2bf(b) << 16);
}

// ---------------------------------------------------------------------------
// K0 gat_pack v2: m13-textbook dense mask builder.  R8 post-mortem: the old
// pack ran 2TB/s with 2.5x write amplification because each 16B store
// instruction had lanes at 64B stride (partial lines + NT = HBM RMW).  The
// fill/m13 kernels (6.3-6.5TB/s) have each wave instruction covering a
// dense 1KB run -- per-instruction density is the whole game.  Here: one
// f32x4 per lane per step, consecutive lanes = consecutive 16B (1KB/instr
// dense reads).  Mask: 4-bit nibble + 3 shfl_xor, lanes t%4==0 store u16
// (32B/wave dense).  outA is NOT written here -- it rides fused's compute.
// grid 2048x256, 24 steps, f32x4 count = 12,582,912 = 524288*24 exactly.
// ---------------------------------------------------------------------------
__global__ __launch_bounds__(256) void gat_pack(
    const float* __restrict__ Ag, unsigned short* __restrict__ Amask)
{
    const int t = threadIdx.x;
    const size_t base0 = (size_t)blockIdx.x * 256 + t;
    #pragma unroll 1
    for (int it = 0; it < 24; ++it) {
        const size_t gi = base0 + (size_t)it * (2048 * 256);   // f32x4 index
        f32x4 a = *(const f32x4*)(Ag + gi * 4);
        unsigned int nib = 0;
        #pragma unroll
        for (int r = 0; r < 4; ++r)
            nib |= (a[r] != 0.f ? 1u : 0u) << r;
        unsigned int b1 = (unsigned int)__shfl_xor((int)nib, 1);
        unsigned int b2 = (unsigned int)__shfl_xor((int)nib, 2);
        unsigned int b3 = (unsigned int)__shfl_xor((int)nib, 3);
        if ((t & 3) == 0)
            Amask[gi >> 2] =
                (unsigned short)(nib | (b1 << 4) | (b2 << 8) | (b3 << 12));
    }
}

// ---------------------------------------------------------------------------
// K1: v1/v2 fold of W_emb, s1/s2 per node, per-wave max(s2) -> M2part, and
// permuted bf16 transpose xP (light version, no A traffic).
// grid (16 j-tiles, 48 bp), block 256 (4 waves).
// ---------------------------------------------------------------------------
__global__ __launch_bounds__(256) void gat_pre(
    const float* __restrict__ x, const float* __restrict__ Wemb,
    const float* __restrict__ a1, const float* __restrict__ a2,
    float* __restrict__ s1g, float* __restrict__ s2g,
    unsigned short* __restrict__ xP, float* __restrict__ M2part)
{
    __shared__ float xs[64][65];
    __shared__ float vs[2][64];
    const int t = threadIdx.x, l = t & 63, w = t >> 6;
    const int j0 = blockIdx.x * 64;
    const int bp = blockIdx.y;

    if (w == 0) {   // v1[c]=sum_h a1[h]*W_emb[h][c]  (x_emb folds away)
        float v1 = 0.f, v2 = 0.f;
        #pragma unroll 8
        for (int h = 0; h < 64; ++h) {
            float we = Wemb[h * 64 + l];
            v1 = fmaf(a1[h], we, v1);
            v2 = fmaf(a2[h], we, v2);
        }
        vs[0][l] = v1; vs[1][l] = v2;
    }
    const float* xb = x + ((size_t)bp * N_ + j0) * C_;
    #pragma unroll
    for (int it = 0; it < 16; ++it)
        xs[it * 4 + w][l] = xb[(it * 4 + w) * C_ + l];
    __syncthreads();

    const int jr = t >> 2, c0 = (t & 3) * 16;
    float p1 = 0.f, p2 = 0.f;
    #pragma unroll
    for (int k = 0; k < 16; ++k) {
        float xv = xs[jr][c0 + k];
        p1 = fmaf(xv, vs[0][c0 + k], p1);
        p2 = fmaf(xv, vs[1][c0 + k], p2);
    }
    p1 += __shfl_xor(p1, 1); p1 += __shfl_xor(p1, 2);
    p2 += __shfl_xor(p2, 1); p2 += __shfl_xor(p2, 2);
    if ((l & 3) == 0) {
        s1g[bp * N_ + j0 + jr] = p1;
        s2g[bp * N_ + j0 + jr] = p2;
    }
    float m = p2;
    m = fmaxf(m, __shfl_xor(m, 4));
    m = fmaxf(m, __shfl_xor(m, 8));
    m = fmaxf(m, __shfl_xor(m, 16));
    m = fmaxf(m, __shfl_xor(m, 32));
    if (l == 0) M2part[bp * 64 + blockIdx.x * 4 + w] = m;

    // permuted transpose store: source j_local = part*16 + 4m + i  ->
    // dest  d = (part>>1)*32 + (part&1)*4 + m*8 + i   (within this 64-chunk)
    const int c = t >> 2, part = t & 3;
    unsigned short* dstb = xP + (size_t)bp * C_ * N_ + (size_t)c * N_ + j0 +
                           (part >> 1) * 32 + (part & 1) * 4;
    #pragma unroll
    for (int m_ = 0; m_ < 4; ++m_) {
        unsigned int lo = pack2(xs[part * 16 + 4 * m_ + 0][c],
                                xs[part * 16 + 4 * m_ + 1][c]);
        unsigned int hi = pack2(xs[part * 16 + 4 * m_ + 2][c],
                                xs[part * 16 + 4 * m_ + 3][c]);
        *(uint2*)&dstb[m_ * 8] = make_uint2(lo, hi);
    }
}

// ---------------------------------------------------------------------------
// K2 v10 (= R7's verified fused): mask-read compute + outA reconstruction.
// Reads: 8B mask word per (row,chunk) from the L3-hot 6.3MB bitmask, xP
// from L2.  Writes: outA = bit?1.0:0.0 (bit-exact, A in {0,1}) with PLAIN
// stores -- each u16's 64B line is completed by the 4 q-lanes of a single
// instruction, so L2 merges to full lines (R7 WRITE was clean ~211MB).
// Stores are fire-and-forget; SB-pinned order keeps all loads older than
// stores so counted load-waits never drain them.  R7 arithmetic put this
// kernel at ~60us.  P = bit ? Ev : 0 == Av*Ev exactly.
// grid (16,48), block 256 (4 indep waves), launch_bounds(256,3).
// ---------------------------------------------------------------------------
#define SB() __builtin_amdgcn_sched_barrier(0)

__global__ __launch_bounds__(256, 3) void gat_fused(
    const unsigned short* __restrict__ Amask, float* __restrict__ outA,
    const unsigned short* __restrict__ xP,
    const float* __restrict__ s1g, const float* __restrict__ s2g,
    const float* __restrict__ M2part,
    const float* __restrict__ Wlin, float* __restrict__ out)
{
    __shared__ unsigned short aggLDS[4][16][72]; // 9 KB  epilogue only (pad 8)
    __shared__ float s2lds[1024];                // 4 KB  s2 row, block-shared
    __shared__ float lsLDS[4][16];               // 256 B per-wave row sums

    const int t = threadIdx.x, l = t & 63, w = t >> 6;
    const int i15 = l & 15, q = l >> 4;
    const int bp = blockIdx.y;
    const int ibase = blockIdx.x * 64 + w * 16;

    // stage s2 (1024 f32) to LDS, block-wide
    *(f32x4*)&s2lds[4 * t] = *(const f32x4*)&s2g[bp * N_ + 4 * t];

    float m2v = M2part[bp * 64 + l];
    #pragma unroll
    for (int off = 32; off >= 1; off >>= 1)
        m2v = fmaxf(m2v, __shfl_xor(m2v, off));
    const float M2 = m2v;
    // this lane owns output row (ibase + i15) exclusively
    const float s1_l = s1g[bp * N_ + ibase + i15];
    const float zr = s1_l + M2;
    const float mv = fmaxf(zr, 0.01f * zr);   // global max_j leaky(s1+s2j)

    __syncthreads();   // s2lds ready (only barrier before epilogue)

    float* oArow = outA + ((size_t)bp * N_ + ibase + i15) * N_ + q * 4;
    const unsigned short* xProw = xP + (size_t)bp * C_ * N_ + (size_t)i15 * N_ + q * 8;
    // mask row: u16[64] per row; chunk k bits = 8B at offset k
    const uint2* Mrow = (const uint2*)(Amask + ((size_t)bp * N_ + ibase + i15) * 64);

    f32x4 acc[4] = {};          // D: row q*4+r, col nt*16+i15
    float ls = 0.f;             // partial row-sum of row i15 (this lane's j's)
    const int q4 = q * 4;

    bf16x8 Xa[8], Xb[8];        // xP fragment double-buffer [s*4+nt]
    uint2 Ma, Mb;               // mask double-buffer (8B per chunk)

#define LOADX(Xc, kk) do {                                                    \
    _Pragma("unroll")                                                         \
    for (int nt = 0; nt < 4; ++nt)                                            \
        _Pragma("unroll")                                                     \
        for (int s = 0; s < 2; ++s)                                           \
            Xc[s * 4 + nt] = *(const bf16x8*)&xProw[(size_t)nt * 16 * N_ +    \
                                                    (kk) * 64 + s * 32];      \
    } while (0)

// consume chunk kk from Xc (xP regs) and Mc (mask bits), loaded >=1 iter ago
#define CONSUME(Xc, Mc, kk) do {                                              \
    const int jrel = (kk) * 64;                                               \
    f32x4 Ev[4];                                                              \
    _Pragma("unroll")                                                         \
    for (int g = 0; g < 4; ++g) {                                             \
        const f32x4 s2v = *(const f32x4*)&s2lds[jrel + g * 16 + q4];          \
        _Pragma("unroll")                                                     \
        for (int r = 0; r < 4; ++r) {                                         \
            float zz = s1_l + s2v[r];                                         \
            zz = fmaxf(zz, 0.01f * zz);                                       \
            Ev[g][r] = __expf(zz - mv);                                       \
        }                                                                     \
    }                                                                         \
    SB();                                                                     \
    f32x4 P[4];                                                               \
    _Pragma("unroll")                                                         \
    for (int g = 0; g < 4; ++g) {                                             \
        const unsigned int wbits = (g < 2) ? Mc.x : Mc.y;                     \
        const int sh = (g & 1) * 16 + q4;                                     \
        f32x4 oAv;                                                            \
        _Pragma("unroll")                                                     \
        for (int r = 0; r < 4; ++r) {                                         \
            float bf = (float)((wbits >> (sh + r)) & 1u);                     \
            oAv[r] = bf;                                                      \
            P[g][r] = bf * Ev[g][r];                                          \
            ls += P[g][r];                                                    \
        }                                                                     \
        *(f32x4*)(oArow + jrel + g * 16) = oAv;                               \
    }                                                                         \
    uint4 u0 = make_uint4(pack2(P[0][0], P[0][1]), pack2(P[0][2], P[0][3]),   \
                          pack2(P[1][0], P[1][1]), pack2(P[1][2], P[1][3]));  \
    uint4 u1 = make_uint4(pack2(P[2][0], P[2][1]), pack2(P[2][2], P[2][3]),   \
                          pack2(P[3][0], P[3][1]), pack2(P[3][2], P[3][3]));  \
    bf16x8 af0 = __builtin_bit_cast(bf16x8, u0);                              \
    bf16x8 af1 = __builtin_bit_cast(bf16x8, u1);                              \
    _Pragma("unroll")                                                         \
    for (int nt = 0; nt < 4; ++nt)                                            \
        acc[nt] = __builtin_amdgcn_mfma_f32_16x16x32_bf16(af0, Xc[nt],        \
                                                          acc[nt], 0, 0, 0);  \
    _Pragma("unroll")                                                         \
    for (int nt = 0; nt < 4; ++nt)                                            \
        acc[nt] = __builtin_amdgcn_mfma_f32_16x16x32_bf16(af1, Xc[4 + nt],    \
                                                          acc[nt], 0, 0, 0);  \
    } while (0)

    // prime chunk 0
    LOADX(Xa, 0); Ma = Mrow[0];
    #pragma unroll 1
    for (int k = 0; k < 16; k += 2) {
        SB();
        Mb = Mrow[k + 1]; LOADX(Xb, k + 1);   // issue BEFORE any chunk-k store
        SB();
        CONSUME(Xa, Ma, k);
        SB();
        if (k + 2 < 16) { Ma = Mrow[k + 2]; LOADX(Xa, k + 2); }
        SB();
        CONSUME(Xb, Mb, k + 1);
    }
    SB();
#undef LOADX
#undef CONSUME

    // row-sum: lane has partial of row i15; combine across the 4 q-groups
    ls += __shfl_xor(ls, 16);
    ls += __shfl_xor(ls, 32);
    if (q == 0) lsLDS[w][i15] = ls;
    const f32x4 lsq = *(const f32x4*)&lsLDS[w][4 * q];   // rows 4q..4q+3

    // ---- epilogue: agg = acc/l, LDS round-trip to A-layout, @W_lin^T, sigmoid
    unsigned short* aggl = &aggLDS[w][0][0];   // stride 72
    #pragma unroll
    for (int nt = 0; nt < 4; ++nt)
        #pragma unroll
        for (int r = 0; r < 4; ++r)
            aggl[(q * 4 + r) * 72 + nt * 16 + i15] = f2bf(acc[nt][r] / lsq[r]);

    f32x4 d2[4] = {};
    #pragma unroll
    for (int s = 0; s < 2; ++s) {
        bf16x8 af = *(const bf16x8*)&aggl[i15 * 72 + s * 32 + q * 8];
        #pragma unroll
        for (int nt = 0; nt < 4; ++nt) {
            const float* wp = Wlin + (size_t)(nt * 16 + i15) * C_ + s * 32 + q * 8;
            f32x4 w0 = *(const f32x4*)wp;
            f32x4 w1 = *(const f32x4*)(wp + 4);
            bf16x8 bfr;
            #pragma unroll
            for (int jj = 0; jj < 4; ++jj) { bfr[jj] = (__bf16)w0[jj]; bfr[4 + jj] = (__bf16)w1[jj]; }
            d2[nt] = __builtin_amdgcn_mfma_f32_16x16x32_bf16(af, bfr, d2[nt], 0, 0, 0);
        }
    }
    float* orow = out + ((size_t)bp * N_ + ibase) * C_;
    #pragma unroll
    for (int nt = 0; nt < 4; ++nt)
        #pragma unroll
        for (int r = 0; r < 4; ++r)
            orow[(size_t)(q * 4 + r) * C_ + nt * 16 + i15] =
                1.f / (1.f + __expf(-d2[nt][r]));
}

extern "C" void kernel_launch(void* const* d_in, const int* in_sizes, int n_in,
                              void* d_out, int out_size, void* d_ws, size_t ws_size,
                              hipStream_t stream) {
    const float* x    = (const float*)d_in[0];
    const float* Ag   = (const float*)d_in[1];
    const float* Wemb = (const float*)d_in[2];
    const float* a1   = (const float*)d_in[3];
    const float* a2   = (const float*)d_in[4];
    const float* Wlin = (const float*)d_in[5];
    float* out  = (float*)d_out;
    float* outA = out + (size_t)BP_ * N_ * C_;   // tuple output #2: A passthrough

    // ws layout (~13 MB total)
    float* s1g = (float*)d_ws;                               // 48K f32
    float* s2g = s1g + BP_ * N_;                             // 48K f32
    float* M2part = s2g + BP_ * N_;                          // 48*64 f32
    unsigned short* xP = (unsigned short*)(M2part + BP_ * 64);   // 6.3MB bf16
    unsigned short* Amask = xP + (size_t)BP_ * C_ * N_;          // 6.3MB bits

    gat_pack<<<dim3(2048), dim3(256), 0, stream>>>(Ag, Amask);
    gat_pre<<<dim3(16, BP_), dim3(256), 0, stream>>>(x, Wemb, a1, a2,
                                                     s1g, s2g, xP, M2part);
    gat_fused<<<dim3(16, BP_), dim3(256), 0, stream>>>(Amask, outA, xP, s1g, s2g,
                                                       M2part, Wlin, out);
}

// Round 10
// 397.652 us; speedup vs baseline: 1.6352x; 1.0430x over previous
//
#include <hip/hip_runtime.h>

typedef __attribute__((ext_vector_type(8))) __bf16 bf16x8;
typedef __attribute__((ext_vector_type(4))) float f32x4;

#define N_ 1024
#define C_ 64
#define BP_ 48

static __device__ __forceinline__ unsigned short f2bf(float f) {
    __bf16 b = (__bf16)f;
    return __builtin_bit_cast(unsigned short, b);
}
static __device__ __forceinline__ unsigned int pack2(float a, float b) {
    return (unsigned int)f2bf(a) | ((unsigned int)f2bf(b) << 16);
}

// ---------------------------------------------------------------------------
// K1: v1/v2 fold of W_emb, s1/s2 per node, per-wave max(s2) -> M2part, and
// permuted bf16 transpose xP (light version, no A traffic).
// grid (16 j-tiles, 48 bp), block 256 (4 waves).
// ---------------------------------------------------------------------------
__global__ __launch_bounds__(256) void gat_pre(
    const float* __restrict__ x, const float* __restrict__ Wemb,
    const float* __restrict__ a1, const float* __restrict__ a2,
    float* __restrict__ s1g, float* __restrict__ s2g,
    unsigned short* __restrict__ xP, float* __restrict__ M2part)
{
    __shared__ float xs[64][65];
    __shared__ float vs[2][64];
    const int t = threadIdx.x, l = t & 63, w = t >> 6;
    const int j0 = blockIdx.x * 64;
    const int bp = blockIdx.y;

    if (w == 0) {   // v1[c]=sum_h a1[h]*W_emb[h][c]  (x_emb folds away)
        float v1 = 0.f, v2 = 0.f;
        #pragma unroll 8
        for (int h = 0; h < 64; ++h) {
            float we = Wemb[h * 64 + l];
            v1 = fmaf(a1[h], we, v1);
            v2 = fmaf(a2[h], we, v2);
        }
        vs[0][l] = v1; vs[1][l] = v2;
    }
    const float* xb = x + ((size_t)bp * N_ + j0) * C_;
    #pragma unroll
    for (int it = 0; it < 16; ++it)
        xs[it * 4 + w][l] = xb[(it * 4 + w) * C_ + l];
    __syncthreads();

    const int jr = t >> 2, c0 = (t & 3) * 16;
    float p1 = 0.f, p2 = 0.f;
    #pragma unroll
    for (int k = 0; k < 16; ++k) {
        float xv = xs[jr][c0 + k];
        p1 = fmaf(xv, vs[0][c0 + k], p1);
        p2 = fmaf(xv, vs[1][c0 + k], p2);
    }
    p1 += __shfl_xor(p1, 1); p1 += __shfl_xor(p1, 2);
    p2 += __shfl_xor(p2, 1); p2 += __shfl_xor(p2, 2);
    if ((l & 3) == 0) {
        s1g[bp * N_ + j0 + jr] = p1;
        s2g[bp * N_ + j0 + jr] = p2;
    }
    float m = p2;
    m = fmaxf(m, __shfl_xor(m, 4));
    m = fmaxf(m, __shfl_xor(m, 8));
    m = fmaxf(m, __shfl_xor(m, 16));
    m = fmaxf(m, __shfl_xor(m, 32));
    if (l == 0) M2part[bp * 64 + blockIdx.x * 4 + w] = m;

    // permuted transpose store: source j_local = part*16 + 4m + i  ->
    // dest  d = (part>>1)*32 + (part&1)*4 + m*8 + i   (within this 64-chunk)
    const int c = t >> 2, part = t & 3;
    unsigned short* dstb = xP + (size_t)bp * C_ * N_ + (size_t)c * N_ + j0 +
                           (part >> 1) * 32 + (part & 1) * 4;
    #pragma unroll
    for (int m_ = 0; m_ < 4; ++m_) {
        unsigned int lo = pack2(xs[part * 16 + 4 * m_ + 0][c],
                                xs[part * 16 + 4 * m_ + 1][c]);
        unsigned int hi = pack2(xs[part * 16 + 4 * m_ + 2][c],
                                xs[part * 16 + 4 * m_ + 3][c]);
        *(uint2*)&dstb[m_ * 8] = make_uint2(lo, hi);
    }
}

// ---------------------------------------------------------------------------
// K2 v11: single-kernel, in-wave mask pipeline, DENSE-RUN A access.
// R9 lesson: mask-fed compute core ~58-65us (R8 arithmetic) but the split
// pays A's read twice-removed + kernel serialization.  Here the wave loads
// its 16x64 A-panel per chunk as 4 instructions x (4 rows x 256B dense
// runs) -- the per-instruction density of the proven 6.5TB/s streamers,
// vs R0-R6's 16x64B half-line runs.  From the same regs: outA verbatim
// store (dense, bit-exact) + nibble ds_write_b8 into a bank-padded LDS
// table; consumer lanes (i15,q) re-read their row's nibbles (verified
// conflict-free: 4 q-lanes share one word, i15 spreads banks via pad 260).
// lgkmcnt(0)+sched_barrier between write and read (rule 18).  E-block,
// P-build, MFMA, epilogue = verified R9 code.  SB-pinned: loads always
// older than stores -> counted load-waits never drain stores.
// grid (16,48), block 256 (4 indep waves), launch_bounds(256,3) cap 170.
// ---------------------------------------------------------------------------
#define SB() __builtin_amdgcn_sched_barrier(0)

__global__ __launch_bounds__(256, 3) void gat_fused(
    const float* __restrict__ Ag, float* __restrict__ outA,
    const unsigned short* __restrict__ xP,
    const float* __restrict__ s1g, const float* __restrict__ s2g,
    const float* __restrict__ M2part,
    const float* __restrict__ Wlin, float* __restrict__ out)
{
    __shared__ unsigned char nibs[4][16][260];   // 16.3 KB nibble table (pad 4)
    __shared__ unsigned short aggLDS[4][16][72]; // 9 KB  epilogue only (pad 8)
    __shared__ float s2lds[1024];                // 4 KB  s2 row, block-shared
    __shared__ float lsLDS[4][16];               // 256 B per-wave row sums

    const int t = threadIdx.x, l = t & 63, w = t >> 6;
    const int i15 = l & 15, q = l >> 4;
    const int bp = blockIdx.y;
    const int ibase = blockIdx.x * 64 + w * 16;

    // stage s2 (1024 f32) to LDS, block-wide
    *(f32x4*)&s2lds[4 * t] = *(const f32x4*)&s2g[bp * N_ + 4 * t];

    float m2v = M2part[bp * 64 + l];
    #pragma unroll
    for (int off = 32; off >= 1; off >>= 1)
        m2v = fmaxf(m2v, __shfl_xor(m2v, off));
    const float M2 = m2v;
    // this lane owns output row (ibase + i15) exclusively (consumer role)
    const float s1_l = s1g[bp * N_ + ibase + i15];
    const float zr = s1_l + M2;
    const float mv = fmaxf(zr, 0.01f * zr);   // global max_j leaky(s1+s2j)

    __syncthreads();   // s2lds ready (only barrier before epilogue)

    // producer role: lane covers row pr (+4*inst), 16B-unit pc of each 256B run
    const int pr = l >> 4;          // row within 4-row group
    const int pc = l & 15;          // 16B unit within the 256B chunk-row run
    const float* Abase = Ag + ((size_t)bp * N_ + ibase) * N_;
    float* oAbase = outA + ((size_t)bp * N_ + ibase) * N_;
    const unsigned short* xProw = xP + (size_t)bp * C_ * N_ + (size_t)i15 * N_ + q * 8;

    f32x4 acc[4] = {};          // D: row q*4+r, col nt*16+i15
    float ls = 0.f;             // partial row-sum of row i15 (this lane's j's)
    const int q4 = q * 4;

    f32x4 Aa[4], Ab[4];         // A panel double-buffer: [inst] = rows inst*4+pr
    bf16x8 Xa[8], Xb[8];        // xP fragment double-buffer [s*4+nt]

#define LOADX(Xc, kk) do {                                                    \
    _Pragma("unroll")                                                         \
    for (int nt = 0; nt < 4; ++nt)                                            \
        _Pragma("unroll")                                                     \
        for (int s = 0; s < 2; ++s)                                           \
            Xc[s * 4 + nt] = *(const bf16x8*)&xProw[(size_t)nt * 16 * N_ +    \
                                                    (kk) * 64 + s * 32];      \
    } while (0)

// dense A panel load: 4 instr, each 4 rows x 256B contiguous runs
#define LOADA(Ax, kk) do {                                                    \
    _Pragma("unroll")                                                         \
    for (int inst = 0; inst < 4; ++inst)                                      \
        Ax[inst] = *(const f32x4*)(Abase + (size_t)(inst * 4 + pr) * N_ +     \
                                   (kk) * 64 + pc * 4);                       \
    } while (0)

// consume chunk kk from Ac (A panel regs) and Xc (xP regs)
#define CONSUME(Ac, Xc, kk) do {                                              \
    const int jrel = (kk) * 64;                                               \
    /* E block first: s2 ds_reads + exp VALU (A-independent) */               \
    f32x4 Ev[4];                                                              \
    _Pragma("unroll")                                                         \
    for (int g = 0; g < 4; ++g) {                                             \
        const f32x4 s2v = *(const f32x4*)&s2lds[jrel + g * 16 + q4];          \
        _Pragma("unroll")                                                     \
        for (int r = 0; r < 4; ++r) {                                         \
            float zz = s1_l + s2v[r];                                         \
            zz = fmaxf(zz, 0.01f * zz);                                       \
            Ev[g][r] = __expf(zz - mv);                                       \
        }                                                                     \
    }                                                                         \
    SB();                                                                     \
    /* A-dependent head: nibble extract + LDS write + outA passthrough */     \
    _Pragma("unroll")                                                         \
    for (int inst = 0; inst < 4; ++inst) {                                    \
        unsigned int nib = 0;                                                 \
        _Pragma("unroll")                                                     \
        for (int r = 0; r < 4; ++r)                                           \
            nib |= (Ac[inst][r] != 0.f ? 1u : 0u) << r;                       \
        nibs[w][inst * 4 + pr][(kk) * 16 + pc] = (unsigned char)nib;          \
        *(f32x4*)(oAbase + (size_t)(inst * 4 + pr) * N_ + jrel + pc * 4) =    \
            Ac[inst];                                                         \
    }                                                                         \
    asm volatile("s_waitcnt lgkmcnt(0)" ::: "memory");                        \
    SB();                                                                     \
    /* consumer: read own row's nibbles, build P, MFMA */                     \
    f32x4 P[4];                                                               \
    _Pragma("unroll")                                                         \
    for (int g = 0; g < 4; ++g) {                                             \
        const unsigned int nib = nibs[w][i15][(kk) * 16 + g * 4 + q];         \
        _Pragma("unroll")                                                     \
        for (int r = 0; r < 4; ++r) {                                         \
            P[g][r] = ((nib >> r) & 1u) ? Ev[g][r] : 0.f;                     \
            ls += P[g][r];                                                    \
        }                                                                     \
    }                                                                         \
    uint4 u0 = make_uint4(pack2(P[0][0], P[0][1]), pack2(P[0][2], P[0][3]),   \
                          pack2(P[1][0], P[1][1]), pack2(P[1][2], P[1][3]));  \
    uint4 u1 = make_uint4(pack2(P[2][0], P[2][1]), pack2(P[2][2], P[2][3]),   \
                          pack2(P[3][0], P[3][1]), pack2(P[3][2], P[3][3]));  \
    bf16x8 af0 = __builtin_bit_cast(bf16x8, u0);                              \
    bf16x8 af1 = __builtin_bit_cast(bf16x8, u1);                              \
    _Pragma("unroll")                                                         \
    for (int nt = 0; nt < 4; ++nt)                                            \
        acc[nt] = __builtin_amdgcn_mfma_f32_16x16x32_bf16(af0, Xc[nt],        \
                                                          acc[nt], 0, 0, 0);  \
    _Pragma("unroll")                                                         \
    for (int nt = 0; nt < 4; ++nt)                                            \
        acc[nt] = __builtin_amdgcn_mfma_f32_16x16x32_bf16(af1, Xc[4 + nt],    \
                                                          acc[nt], 0, 0, 0);  \
    } while (0)

    // prime chunk 0
    LOADX(Xa, 0); LOADA(Aa, 0);
    #pragma unroll 1
    for (int k = 0; k < 16; k += 2) {
        SB();
        LOADX(Xb, k + 1); LOADA(Ab, k + 1);   // issue BEFORE any chunk-k store
        SB();
        CONSUME(Aa, Xa, k);
        SB();
        if (k + 2 < 16) { LOADX(Xa, k + 2); LOADA(Aa, k + 2); }
        SB();
        CONSUME(Ab, Xb, k + 1);
    }
    SB();
#undef LOADX
#undef LOADA
#undef CONSUME

    // row-sum: lane has partial of row i15; combine across the 4 q-groups
    ls += __shfl_xor(ls, 16);
    ls += __shfl_xor(ls, 32);
    if (q == 0) lsLDS[w][i15] = ls;
    const f32x4 lsq = *(const f32x4*)&lsLDS[w][4 * q];   // rows 4q..4q+3

    // ---- epilogue: agg = acc/l, LDS round-trip to A-layout, @W_lin^T, sigmoid
    unsigned short* aggl = &aggLDS[w][0][0];   // stride 72
    #pragma unroll
    for (int nt = 0; nt < 4; ++nt)
        #pragma unroll
        for (int r = 0; r < 4; ++r)
            aggl[(q * 4 + r) * 72 + nt * 16 + i15] = f2bf(acc[nt][r] / lsq[r]);

    f32x4 d2[4] = {};
    #pragma unroll
    for (int s = 0; s < 2; ++s) {
        bf16x8 af = *(const bf16x8*)&aggl[i15 * 72 + s * 32 + q * 8];
        #pragma unroll
        for (int nt = 0; nt < 4; ++nt) {
            const float* wp = Wlin + (size_t)(nt * 16 + i15) * C_ + s * 32 + q * 8;
            f32x4 w0 = *(const f32x4*)wp;
            f32x4 w1 = *(const f32x4*)(wp + 4);
            bf16x8 bfr;
            #pragma unroll
            for (int jj = 0; jj < 4; ++jj) { bfr[jj] = (__bf16)w0[jj]; bfr[4 + jj] = (__bf16)w1[jj]; }
            d2[nt] = __builtin_amdgcn_mfma_f32_16x16x32_bf16(af, bfr, d2[nt], 0, 0, 0);
        }
    }
    float* orow = out + ((size_t)bp * N_ + ibase) * C_;
    #pragma unroll
    for (int nt = 0; nt < 4; ++nt)
        #pragma unroll
        for (int r = 0; r < 4; ++r)
            orow[(size_t)(q * 4 + r) * C_ + nt * 16 + i15] =
                1.f / (1.f + __expf(-d2[nt][r]));
}

extern "C" void kernel_launch(void* const* d_in, const int* in_sizes, int n_in,
                              void* d_out, int out_size, void* d_ws, size_t ws_size,
                              hipStream_t stream) {
    const float* x    = (const float*)d_in[0];
    const float* Ag   = (const float*)d_in[1];
    const float* Wemb = (const float*)d_in[2];
    const float* a1   = (const float*)d_in[3];
    const float* a2   = (const float*)d_in[4];
    const float* Wlin = (const float*)d_in[5];
    float* out  = (float*)d_out;
    float* outA = out + (size_t)BP_ * N_ * C_;   // tuple output #2: A passthrough

    // ws layout (~6.7 MB total)
    float* s1g = (float*)d_ws;                               // 48K f32
    float* s2g = s1g + BP_ * N_;                             // 48K f32
    float* M2part = s2g + BP_ * N_;                          // 48*64 f32
    unsigned short* xP = (unsigned short*)(M2part + BP_ * 64);   // 6.3MB bf16

    gat_pre<<<dim3(16, BP_), dim3(256), 0, stream>>>(x, Wemb, a1, a2,
                                                     s1g, s2g, xP, M2part);
    gat_fused<<<dim3(16, BP_), dim3(256), 0, stream>>>(Ag, outA, xP, s1g, s2g,
                                                       M2part, Wlin, out);
}